// Round 9
// baseline (608.691 us; speedup 1.0000x reference)
//
#include <hip/hip_runtime.h>
#include <hip/hip_bf16.h>
#include <stdint.h>

// Problem constants (CausalSelfAttention_22703197127379)
#define T_DIM 8192
#define E_DIM 4096
#define NQH   32
#define HD    128
#define QSZ   (NQH * HD)          // 4096
#define QKV_COLS 6144             // Q_SIZE + 2*KV_SIZE (w_qkv leading dim)

typedef unsigned short u16;
typedef __attribute__((ext_vector_type(8))) short   bf16x8;
typedef __attribute__((ext_vector_type(4))) float   f32x4;
typedef __attribute__((ext_vector_type(4))) unsigned short u16x4;

__device__ __forceinline__ u16 f2bf(float f) {
    uint32_t u = __float_as_uint(f);
    u += 0x7fffu + ((u >> 16) & 1u);   // round-to-nearest-even
    return (u16)(u >> 16);
}
__device__ __forceinline__ float bf2f(u16 u) {
    return __uint_as_float(((uint32_t)u) << 16);
}

// async global->LDS, 16 bytes per lane (dest = wave-uniform base + lane*16)
__device__ __forceinline__ void gload_lds16(u16* lds, const u16* g) {
    __builtin_amdgcn_global_load_lds(
        (const __attribute__((address_space(1))) uint32_t*)g,
        (__attribute__((address_space(3))) uint32_t*)lds,
        16, 0, 0);
}

// ---------------- fp32 -> bf16 elementwise convert (vectorized) ----------------
__global__ void convert_f32_bf16(const float* __restrict__ in, u16* __restrict__ out, size_t n4) {
    size_t i = (size_t)blockIdx.x * blockDim.x + threadIdx.x;
    size_t stride = (size_t)gridDim.x * blockDim.x;
    for (; i < n4; i += stride) {
        float4 v = ((const float4*)in)[i];
        u16x4 o;
        o.x = f2bf(v.x); o.y = f2bf(v.y); o.z = f2bf(v.z); o.w = f2bf(v.w);
        ((u16x4*)out)[i] = o;
    }
}

// ---------------- fp32 [K][ldW] (col slice) -> bf16 transposed [N][K] ----------------
__global__ void transpose_conv(const float* __restrict__ W, u16* __restrict__ Wt,
                               int K, int N, int ldW, int colOff) {
    __shared__ float tile[32][33];
    const int tx = threadIdx.x, ty = threadIdx.y;
    const int n0 = blockIdx.x * 32, k0 = blockIdx.y * 32;
#pragma unroll
    for (int j = 0; j < 4; ++j) {
        int k = k0 + ty + j * 8;
        tile[ty + j * 8][tx] = W[(size_t)k * ldW + colOff + n0 + tx];
    }
    __syncthreads();
#pragma unroll
    for (int j = 0; j < 4; ++j) {
        int n = n0 + ty + j * 8;
        Wt[(size_t)n * K + k0 + tx] = f2bf(tile[tx][ty + j * 8]);
    }
}

// ---------------- RoPE cos/sin table: tab[t][d] = (cos, sin)(pos[t]*inv(d)) ---------
// Standalone kernel: libm (powf/sincosf) is safe here; NEVER inside the GEMM
// epilogue (rounds 6/7: ocml call with acc[8][4] live => ABI scratch spills).
__global__ void rope_table(const int* __restrict__ pos, float2* __restrict__ tab) {
    int idx = blockIdx.x * blockDim.x + threadIdx.x;   // T*64 threads
    int t = idx >> 6, d = idx & 63;
    float inv = powf(10000.0f, -(float)d * (1.0f / 64.0f));
    float fr  = (float)pos[t] * inv;
    float s, c;
    sincosf(fr, &s, &c);
    tab[idx] = make_float2(c, s);
}

// =============== m201-style 2-barrier same-phase 8-phase bf16 GEMM ===============
// C[M][N] = A[M][K] * Bt[N][K]^T. 256x256 tile, BK=64, 8 waves (2M x 4N),
// 2 K-tile LDS buffers (128 KiB), 1 block/CU.
// Per phase: {ds_reads (same-phase operands) ; stage 1 half-tile ; [vmcnt] ;
//   sched_bar ; s_barrier ; lgkmcnt(0) ; sched_bar ; setprio+16 MFMA ; s_barrier}
// Quadrants per tile t (buf=t&1): P0:Q00(reads a03+b01,12) P1:Q40(a47,8)
//   P2:Q02(b23,4) P3:Q42(0 reads). Single-set fragment regs (read->use gap 0).
// Stage (into buf^1): A0@P0, A1@P1, B0@P2, B1@P3 (of tile t+1).
// vmcnt ledger (2 loads per half-tile):
//   entry invariant @P0(t): in-flight = [B1(t)].
//   P1: after stage -> [B1(t),A0,A1(t+1)]=6; vmcnt(4) drains B1(t) (b23 read @P2). 
//   P3: after stage -> [A0,A1,B0,B1(t+1)]=8; vmcnt(2) drains A0,A1,B0(t+1)
//       (a03/b01 read @next P0), leaves B1(t+1) -> invariant.
// Every load rides >=2 phases (~1650cy > 900cy HBM). Never vmcnt(0) in loop.
// Write-hazards: each stage writes opposite-parity buf whose last reads
// completed >=2 barriers earlier (skew bounded by per-phase barriers).
__device__ __forceinline__ void store_out(u16* p, float v)  { *p = f2bf(v); }
__device__ __forceinline__ void store_out(float* p, float v){ *p = v; }

#define VMC(N)  asm volatile("s_waitcnt vmcnt(%0)"  :: "n"(N) : "memory")
#define LGKM(N) asm volatile("s_waitcnt lgkmcnt(%0)" :: "n"(N) : "memory")
#define PHASE_SYNC() do { __builtin_amdgcn_sched_barrier(0); __builtin_amdgcn_s_barrier(); \
                          LGKM(0); __builtin_amdgcn_sched_barrier(0); } while (0)
#define ENDBAR() do { __builtin_amdgcn_sched_barrier(0); __builtin_amdgcn_s_barrier(); } while (0)

// stage one half-tile (128 rows x 64 K, one operand): 2 gloads/thread
#define STG_A(buf, h, kOff) do { \
    const u16* s_ = sA + (size_t)(h) * 128 * K + (kOff); \
    u16* d_ = dL + (buf) * 32768 + (h) * 8192; \
    gload_lds16(d_, s_); gload_lds16(d_ + 4096, s_ + (size_t)64 * K); } while (0)
#define STG_B(buf, h, kOff) do { \
    const u16* s_ = sB + (size_t)(h) * 128 * K + (kOff); \
    u16* d_ = dL + 16384 + (buf) * 32768 + (h) * 8192; \
    gload_lds16(d_, s_); gload_lds16(d_ + 4096, s_ + (size_t)64 * K); } while (0)

// read A frags mi in [miBase, miBase+4), both K-slices
#define RD_A(buf, miBase, d0, d1) do { _Pragma("unroll") \
    for (int m = 0; m < 4; ++m) { \
        const u16* p_ = lds + (buf) * 32768 + wm * 8192 + ((miBase) + m) * 1024 + aRow; \
        d0[m] = *(const bf16x8*)(p_ + cOf0); \
        d1[m] = *(const bf16x8*)(p_ + cOf1); } } while (0)
// read B frags ni in [niBase, niBase+2), both K-slices.
// B-row = ni*64 + wn*16 + lr -> half = ni>>1, row_in_half = (ni&1)*64+wn*16+lr
#define RD_B(buf, niBase, d0, d1) do { _Pragma("unroll") \
    for (int n = 0; n < 2; ++n) { \
        const int ni_ = (niBase) + n; \
        const u16* p_ = lds + (buf) * 32768 + 16384 + (ni_ >> 1) * 8192 + \
                        ((ni_ & 1) * 64 + wn * 16) * 64 + aRow; \
        d0[n] = *(const bf16x8*)(p_ + cOf0); \
        d1[n] = *(const bf16x8*)(p_ + cOf1); } } while (0)

#define MM(miBase, niBase, A0, A1, B0, B1) do { \
    __builtin_amdgcn_s_setprio(1); \
    _Pragma("unroll") for (int m = 0; m < 4; ++m) \
    _Pragma("unroll") for (int n = 0; n < 2; ++n) { \
        acc[(miBase) + m][(niBase) + n] = __builtin_amdgcn_mfma_f32_16x16x32_bf16( \
            A0[m], B0[n], acc[(miBase) + m][(niBase) + n], 0, 0, 0); \
        acc[(miBase) + m][(niBase) + n] = __builtin_amdgcn_mfma_f32_16x16x32_bf16( \
            A1[m], B1[n], acc[(miBase) + m][(niBase) + n], 0, 0, 0); } \
    __builtin_amdgcn_s_setprio(0); } while (0)

// one K-tile (4 phases) reading buf BUF, staging tile@KN into BUF^1
#define TILE(BUF, KN) do {                                                     \
    /* P0: Q00 */                                                              \
    RD_A(BUF, 0, a0K0, a0K1);                                                  \
    RD_B(BUF, 0, b01K0, b01K1);                                                \
    STG_A((BUF) ^ 1, 0, KN);                                                   \
    LGKM(8);                                                                   \
    PHASE_SYNC();                                                              \
    MM(0, 0, a0K0, a0K1, b01K0, b01K1);                                        \
    ENDBAR();                                                                  \
    /* P1: Q40 */                                                              \
    RD_A(BUF, 4, a4K0, a4K1);                                                  \
    STG_A((BUF) ^ 1, 1, KN);                                                   \
    VMC(4);                                                                    \
    PHASE_SYNC();                                                              \
    MM(4, 0, a4K0, a4K1, b01K0, b01K1);                                        \
    ENDBAR();                                                                  \
    /* P2: Q02 */                                                              \
    RD_B(BUF, 2, b23K0, b23K1);                                                \
    STG_B((BUF) ^ 1, 0, KN);                                                   \
    PHASE_SYNC();                                                              \
    MM(0, 2, a0K0, a0K1, b23K0, b23K1);                                        \
    ENDBAR();                                                                  \
    /* P3: Q42 */                                                              \
    STG_B((BUF) ^ 1, 1, KN);                                                   \
    VMC(2);                                                                    \
    PHASE_SYNC();                                                              \
    MM(4, 2, a4K0, a4K1, b23K0, b23K1);                                        \
    ENDBAR();                                                                  \
  } while (0)

template <typename OutT, bool ROPE>
__global__ __launch_bounds__(512, 2) void gemm256(const u16* __restrict__ A,
                                                  const u16* __restrict__ Bt,
                                                  OutT* __restrict__ C,
                                                  const float2* __restrict__ tab,
                                                  int M, int N, int K) {
    __shared__ u16 lds[65536];   // 2 bufs x (A 256x64 + B 256x64) bf16 = 128 KiB
    const int tid  = threadIdx.x;
    const int lane = tid & 63;
    const int wid  = tid >> 6;
    const int wm = wid >> 2;           // 0..1 -> 128 rows each
    const int wn = wid & 3;            // 0..3 -> 16-col granules (col=ni*64+wn*16+lr)
    const int lr  = lane & 15;
    const int kq  = lane >> 4;         // 0..3
    const int lr7 = lr & 7;
    const int aRow = lr * 64;                       // row offset within half (elems)
    const int cOf0 = ((kq) ^ lr7) << 3;             // K-slice 0 chunk (swizzled)
    const int cOf1 = ((4 + kq) ^ lr7) << 3;         // K-slice 1 chunk

    // XCD-bijective block swizzle (gridDim.x % 8 == 0)
    const int nwg = gridDim.x;
    const int cpx = nwg >> 3;
    const int bid = blockIdx.x;
    const int swz = (bid & 7) * cpx + (bid >> 3);
    const int numM = M >> 8;
    const size_t rowBase = (size_t)(swz % numM) << 8;
    const size_t colBase = (size_t)(swz / numM) << 8;

    // staging addresses: half-tile = 1024 chunks of 16B; thread owns chunks
    // tid (row r0=tid>>3) and tid+512 (row r0+64); src col pre-swizzled.
    const int r0 = tid >> 3;
    const int cS = (((tid & 7) ^ (r0 & 7)) << 3);
    const u16* sA = A  + (rowBase + r0) * (size_t)K + cS;
    const u16* sB = Bt + (colBase + r0) * (size_t)K + cS;
    u16* dL = &lds[0] + tid * 8;       // linear chunk dest (+4096 elems for chunk tid+512)

    f32x4 acc[8][4];
#pragma unroll
    for (int i = 0; i < 8; ++i)
#pragma unroll
        for (int j = 0; j < 4; ++j)
            acc[i][j] = (f32x4){0.f, 0.f, 0.f, 0.f};

    bf16x8 a0K0[4], a0K1[4], a4K0[4], a4K1[4];
    bf16x8 b01K0[2], b01K1[2], b23K0[2], b23K1[2];

    // prologue: tile0 -> buf0 (A0,A1,B0,B1 = 8 loads); vmcnt(2) drains
    // A0,A1,B0 (leaves B1(0) riding = steady-state entry invariant); publish.
    STG_A(0, 0, 0); STG_A(0, 1, 0); STG_B(0, 0, 0);
    STG_B(0, 1, 0);
    VMC(2);
    __builtin_amdgcn_sched_barrier(0);
    __builtin_amdgcn_s_barrier();
    __builtin_amdgcn_sched_barrier(0);

    const int nT = K >> 6;             // K/64 tiles, even (K % 128 == 0)
    for (int t = 0; t < nT; t += 2) {
        const int kN1 = (t + 1) << 6;                            // always < K
        const int kN2 = (t + 2 < nT) ? ((t + 2) << 6) : 0;       // clamp OOB tail
        TILE(0, kN1);
        TILE(1, kN2);
    }
    VMC(0);   // drain leftover (clamped) stages before endpgm

    // epilogue: C/D frag layout col = lane&15, row = 4*(lane>>4) + r.
    // Global col = colBase + ni*64 + wn*16 + lr.
    if constexpr (ROPE) {
        const int dIdx = wn * 16 + lr;                   // uniform per lane
#pragma unroll
        for (int mi = 0; mi < 8; ++mi)
#pragma unroll
            for (int r = 0; r < 4; ++r) {
                size_t row = rowBase + wm * 128 + mi * 16 + (kq << 2) + r;
                float2 cs = tab[row * 64 + dIdx];        // (cos, sin) — no libm here
#pragma unroll
                for (int hp = 0; hp < 2; ++hp) {
                    float x1 = acc[mi][hp * 2 + 0][r];
                    float x2 = acc[mi][hp * 2 + 1][r];
                    size_t c1 = colBase + hp * 128 + wn * 16 + lr;
                    C[row * (size_t)N + c1]      = f2bf(x1 * cs.x - x2 * cs.y);
                    C[row * (size_t)N + c1 + 64] = f2bf(x2 * cs.x + x1 * cs.y);
                }
            }
    } else {
#pragma unroll
        for (int mi = 0; mi < 8; ++mi)
#pragma unroll
            for (int ni = 0; ni < 4; ++ni)
#pragma unroll
                for (int r = 0; r < 4; ++r) {
                    size_t row = rowBase + wm * 128 + mi * 16 + (kq << 2) + r;
                    size_t col = colBase + ni * 64 + wn * 16 + lr;
                    store_out(&C[row * (size_t)N + col], acc[mi][ni][r]);
                }
    }
}

extern "C" void kernel_launch(void* const* d_in, const int* in_sizes, int n_in,
                              void* d_out, int out_size, void* d_ws, size_t ws_size,
                              hipStream_t stream) {
    const float* hidden    = (const float*)d_in[0];   // [T][E] fp32
    const int*   positions = (const int*)d_in[1];     // [T] int32
    const float* w_qkv     = (const float*)d_in[2];   // [E][6144] fp32
    const float* w_o       = (const float*)d_in[3];   // [QSZ][E] fp32
    float* out = (float*)d_out;                       // [T][E] fp32

    // workspace layout (bf16): H 64MB | WqT 32MB | WoT 32MB | Q 64MB = 192MB.
    // RoPE table (4MB float2) ALIASES the WoT region: table live only during
    // GEMM1; WoT transpose runs AFTER GEMM1.
    u16* Hb  = (u16*)d_ws;
    u16* WqT = Hb  + (size_t)T_DIM * E_DIM;
    u16* WoT = WqT + (size_t)QSZ * E_DIM;
    u16* Qb  = WoT + (size_t)E_DIM * QSZ;
    float2* tab = (float2*)WoT;

    // 1) hidden fp32 -> bf16
    convert_f32_bf16<<<2048, 256, 0, stream>>>(hidden, Hb, (size_t)T_DIM * E_DIM / 4);

    // 2) Wq transpose+convert, RoPE table (into WoT space)
    dim3 tb(32, 8);
    transpose_conv<<<dim3(QSZ / 32, E_DIM / 32), tb, 0, stream>>>(w_qkv, WqT, E_DIM, QSZ, QKV_COLS, 0);
    rope_table<<<(T_DIM * 64) / 256, 256, 0, stream>>>(positions, tab);

    // 3) Q = rope(H @ Wq)  (bf16 out, table-lookup RoPE fused in epilogue)
    gemm256<u16, true><<<dim3((T_DIM / 256) * (QSZ / 256)), 512, 0, stream>>>(
        Hb, WqT, Qb, tab, T_DIM, QSZ, E_DIM);

    // 4) Wo transpose+convert (overwrites table region — table now dead)
    transpose_conv<<<dim3(E_DIM / 32, QSZ / 32), tb, 0, stream>>>(w_o, WoT, QSZ, E_DIM, E_DIM, 0);

    // 5) out = Q @ Wo  (fp32 out)
    gemm256<float, false><<<dim3((T_DIM / 256) * (E_DIM / 256)), 512, 0, stream>>>(
        Qb, WoT, out, nullptr, T_DIM, E_DIM, QSZ);
}

// Round 10
// 573.153 us; speedup vs baseline: 1.0620x; 1.0620x over previous
//
#include <hip/hip_runtime.h>
#include <hip/hip_bf16.h>
#include <stdint.h>

// Problem constants (CausalSelfAttention_22703197127379)
#define T_DIM 8192
#define E_DIM 4096
#define NQH   32
#define HD    128
#define QSZ   (NQH * HD)          // 4096
#define QKV_COLS 6144             // Q_SIZE + 2*KV_SIZE (w_qkv leading dim)

typedef unsigned short u16;
typedef __attribute__((ext_vector_type(8))) short   bf16x8;
typedef __attribute__((ext_vector_type(4))) float   f32x4;
typedef __attribute__((ext_vector_type(4))) unsigned short u16x4;

__device__ __forceinline__ u16 f2bf(float f) {
    uint32_t u = __float_as_uint(f);
    u += 0x7fffu + ((u >> 16) & 1u);   // round-to-nearest-even
    return (u16)(u >> 16);
}
__device__ __forceinline__ float bf2f(u16 u) {
    return __uint_as_float(((uint32_t)u) << 16);
}

// async global->LDS, 16 bytes per lane (dest = wave-uniform base + lane*16)
__device__ __forceinline__ void gload_lds16(u16* lds, const u16* g) {
    __builtin_amdgcn_global_load_lds(
        (const __attribute__((address_space(1))) uint32_t*)g,
        (__attribute__((address_space(3))) uint32_t*)lds,
        16, 0, 0);
}

// ---------------- fp32 -> bf16 elementwise convert (vectorized) ----------------
__global__ void convert_f32_bf16(const float* __restrict__ in, u16* __restrict__ out, size_t n4) {
    size_t i = (size_t)blockIdx.x * blockDim.x + threadIdx.x;
    size_t stride = (size_t)gridDim.x * blockDim.x;
    for (; i < n4; i += stride) {
        float4 v = ((const float4*)in)[i];
        u16x4 o;
        o.x = f2bf(v.x); o.y = f2bf(v.y); o.z = f2bf(v.z); o.w = f2bf(v.w);
        ((u16x4*)out)[i] = o;
    }
}

// ---------------- fp32 [K][ldW] (col slice) -> bf16 transposed [N][K] ----------------
__global__ void transpose_conv(const float* __restrict__ W, u16* __restrict__ Wt,
                               int K, int N, int ldW, int colOff) {
    __shared__ float tile[32][33];
    const int tx = threadIdx.x, ty = threadIdx.y;
    const int n0 = blockIdx.x * 32, k0 = blockIdx.y * 32;
#pragma unroll
    for (int j = 0; j < 4; ++j) {
        int k = k0 + ty + j * 8;
        tile[ty + j * 8][tx] = W[(size_t)k * ldW + colOff + n0 + tx];
    }
    __syncthreads();
#pragma unroll
    for (int j = 0; j < 4; ++j) {
        int n = n0 + ty + j * 8;
        Wt[(size_t)n * K + k0 + tx] = f2bf(tile[tx][ty + j * 8]);
    }
}

// ---------------- RoPE cos/sin table: tab[t][d] = (cos, sin)(pos[t]*inv(d)) ---------
// Standalone kernel: libm (powf/sincosf) is safe here; NEVER inside the GEMM
// epilogue (rounds 6/7: ocml call with acc[8][4] live => ABI scratch spills).
__global__ void rope_table(const int* __restrict__ pos, float2* __restrict__ tab) {
    int idx = blockIdx.x * blockDim.x + threadIdx.x;   // T*64 threads
    int t = idx >> 6, d = idx & 63;
    float inv = powf(10000.0f, -(float)d * (1.0f / 64.0f));
    float fr  = (float)pos[t] * inv;
    float s, c;
    sincosf(fr, &s, &c);
    tab[idx] = make_float2(c, s);
}

// ============ balanced-read one-ahead 8-phase bf16 GEMM (r8 skeleton) ============
// C[M][N] = A[M][K] * Bt[N][K]^T. 256x256 tile, BK=64, 8 waves (2M x 4N),
// 2 K-tile LDS buffers (128 KiB), 1 block/CU, 1 barrier per phase.
// Per-tile clusters (16 MFMA each): C0=(m0-3,K0) C1=(m4-7,K0) C2=(m0-3,K1)
// C3=(m4-7,K1), all 4 N-frags per cluster. One-ahead reads, 4/8/4/8 per phase
// (vs r8's 12/8/4/0 bursts — P3's 1152cy LDS burst exceeded the 620cy MFMA
// shadow; balanced max is 768cy).
//   P0: stage A0,A1(t+1); BAR; rd{a47K0 4};           MM C0(a03K0,bK0)
//   P1: stage B0,B1(t+1); BAR; rd{a03K1 4, bK1 4};    MM C1(a47K0,bK0)
//   P2:                   BAR; rd{a47K1 4};           MM C2(a03K1,bK1)
//   P3: VMC(0);           BAR; rd{a03K0,bK0 (t+1) 8}; MM C3(a47K1,bK1)
// vmcnt ledger: at P3, in-flight = A0A1(t+1) (issued P0, 3 phases ~2700cy old)
//   + B0B1(t+1) (issued P1, ~1800cy old); both > ~900cy HBM latency => the
//   vmcnt(0) is a count-drain, not a stall. P3's reads then touch buf^1 legally
//   (barrier after vmcnt publishes all waves' stages).
// Write-after-read: stage@P0 writes buf^1 (A-halves) whose last A-read was
//   @P2(t-1) — 2 barriers earlier; stage@P1 (B-halves) vs last B-read @P1(t-1)
//   — 4 barriers. Safe.
// Reads@p are consumed @p+1 (one barrier later) — compiler emits exact lgkmcnt.
// Frag live ranges: <=4 sets x 16 VGPR simultaneously (vs r8's ~112) — no
// spill risk (rounds 6/7 lesson: watch the 256-reg VGPR+AGPR cliff).
__device__ __forceinline__ void store_out(u16* p, float v)  { *p = f2bf(v); }
__device__ __forceinline__ void store_out(float* p, float v){ *p = v; }

#define VMC(N)  asm volatile("s_waitcnt vmcnt(%0)"  :: "n"(N) : "memory")
#define BARS()  do { __builtin_amdgcn_sched_barrier(0); __builtin_amdgcn_s_barrier(); } while (0)
#define BARSPUB() do { __builtin_amdgcn_sched_barrier(0); __builtin_amdgcn_s_barrier(); \
                       __builtin_amdgcn_sched_barrier(0); } while (0)

// stage one half-tile (128 rows x 64 K, one operand): 2 gloads/thread
#define STG_A(buf, h, kOff) do { \
    const u16* s_ = sA + (size_t)(h) * 128 * K + (kOff); \
    u16* d_ = dL + (buf) * 32768 + (h) * 8192; \
    gload_lds16(d_, s_); gload_lds16(d_ + 4096, s_ + (size_t)64 * K); } while (0)
#define STG_B(buf, h, kOff) do { \
    const u16* s_ = sB + (size_t)(h) * 128 * K + (kOff); \
    u16* d_ = dL + 16384 + (buf) * 32768 + (h) * 8192; \
    gload_lds16(d_, s_); gload_lds16(d_ + 4096, s_ + (size_t)64 * K); } while (0)

// read 4 A frags [miBase..miBase+4) of ONE k-slice (OF = cOf0 or cOf1)
#define RD_A4(buf, miBase, OF, dst) do { _Pragma("unroll") \
    for (int m = 0; m < 4; ++m) { \
        dst[m] = *(const bf16x8*)&lds[(buf) * 32768 + wm * 8192 + \
                                      ((miBase) + m) * 1024 + aRow + (OF)]; } } while (0)
// read all 4 B frags of ONE k-slice. B-row = ni*64 + wn*16 + lr
#define RD_B4(buf, OF, dst) do { _Pragma("unroll") \
    for (int n = 0; n < 4; ++n) { \
        dst[n] = *(const bf16x8*)&lds[(buf) * 32768 + 16384 + (n >> 1) * 8192 + \
                                      ((n & 1) * 64 + wn * 16) * 64 + aRow + (OF)]; } } while (0)

// 16 MFMA: 4 M-frags x 4 N-frags, one k-slice
#define MM16(miBase, Af, Bf) do { \
    __builtin_amdgcn_s_setprio(1); \
    _Pragma("unroll") for (int m = 0; m < 4; ++m) \
    _Pragma("unroll") for (int n = 0; n < 4; ++n) \
        acc[(miBase) + m][n] = __builtin_amdgcn_mfma_f32_16x16x32_bf16( \
            Af[m], Bf[n], acc[(miBase) + m][n], 0, 0, 0); \
    __builtin_amdgcn_s_setprio(0); } while (0)

// one K-tile (4 phases) reading buf BUF; stages tile@KN into BUF^1; P3 reads
// next tile's C0 operands from BUF^1.
#define TILE(BUF, KN) do {                                                     \
    /* P0 */                                                                   \
    STG_A((BUF) ^ 1, 0, KN); STG_A((BUF) ^ 1, 1, KN);                          \
    BARS();                                                                    \
    RD_A4(BUF, 4, cOf0, aX);                                                   \
    MM16(0, aC, bK0);                                                          \
    /* P1 */                                                                   \
    STG_B((BUF) ^ 1, 0, KN); STG_B((BUF) ^ 1, 1, KN);                          \
    BARS();                                                                    \
    RD_A4(BUF, 0, cOf1, aY);                                                   \
    RD_B4(BUF, cOf1, bK1);                                                     \
    MM16(4, aX, bK0);                                                          \
    /* P2 */                                                                   \
    BARS();                                                                    \
    RD_A4(BUF, 4, cOf1, aZ);                                                   \
    MM16(0, aY, bK1);                                                          \
    /* P3 */                                                                   \
    VMC(0);                                                                    \
    BARSPUB();                                                                 \
    RD_A4((BUF) ^ 1, 0, cOf0, aC);                                             \
    RD_B4((BUF) ^ 1, cOf0, bK0);                                               \
    MM16(4, aZ, bK1);                                                          \
  } while (0)

template <typename OutT, bool ROPE>
__global__ __launch_bounds__(512, 2) void gemm256(const u16* __restrict__ A,
                                                  const u16* __restrict__ Bt,
                                                  OutT* __restrict__ C,
                                                  const float2* __restrict__ tab,
                                                  int M, int N, int K) {
    __shared__ u16 lds[65536];   // 2 bufs x (A 256x64 + B 256x64) bf16 = 128 KiB
    const int tid  = threadIdx.x;
    const int lane = tid & 63;
    const int wid  = tid >> 6;
    const int wm = wid >> 2;           // 0..1 -> 128 rows each
    const int wn = wid & 3;            // 0..3 -> 16-col granules (col=ni*64+wn*16+lr)
    const int lr  = lane & 15;
    const int kq  = lane >> 4;         // 0..3
    const int lr7 = lr & 7;
    const int aRow = lr * 64;                       // row offset within half (elems)
    const int cOf0 = ((kq) ^ lr7) << 3;             // K-slice 0 chunk (swizzled)
    const int cOf1 = ((4 + kq) ^ lr7) << 3;         // K-slice 1 chunk

    // XCD-bijective block swizzle (gridDim.x % 8 == 0)
    const int nwg = gridDim.x;
    const int cpx = nwg >> 3;
    const int bid = blockIdx.x;
    const int swz = (bid & 7) * cpx + (bid >> 3);
    const int numM = M >> 8;
    const size_t rowBase = (size_t)(swz % numM) << 8;
    const size_t colBase = (size_t)(swz / numM) << 8;

    // staging addresses: half-tile = 1024 chunks of 16B; thread owns chunks
    // tid (row r0=tid>>3) and tid+512 (row r0+64); src col pre-swizzled.
    const int r0 = tid >> 3;
    const int cS = (((tid & 7) ^ (r0 & 7)) << 3);
    const u16* sA = A  + (rowBase + r0) * (size_t)K + cS;
    const u16* sB = Bt + (colBase + r0) * (size_t)K + cS;
    u16* dL = &lds[0] + tid * 8;       // linear chunk dest (+4096 elems for chunk tid+512)

    f32x4 acc[8][4];
#pragma unroll
    for (int i = 0; i < 8; ++i)
#pragma unroll
        for (int j = 0; j < 4; ++j)
            acc[i][j] = (f32x4){0.f, 0.f, 0.f, 0.f};

    bf16x8 aC[4], aX[4], aY[4], aZ[4];   // a03K0 / a47K0 / a03K1 / a47K1
    bf16x8 bK0[4], bK1[4];

    // prologue: tile0 -> buf0 (8 gloads); full drain; publish; pre-read C0
    // operands (a03K0 + bAllK0 of tile0).
    STG_A(0, 0, 0); STG_A(0, 1, 0); STG_B(0, 0, 0); STG_B(0, 1, 0);
    VMC(0);
    BARSPUB();
    RD_A4(0, 0, cOf0, aC);
    RD_B4(0, cOf0, bK0);

    const int nT = K >> 6;             // K/64 tiles, even (K % 128 == 0)
    for (int t = 0; t < nT; t += 2) {
        const int kN1 = (t + 1) << 6;                            // always < K
        const int kN2 = (t + 2 < nT) ? ((t + 2) << 6) : 0;       // clamp OOB tail
        TILE(0, kN1);
        TILE(1, kN2);
    }
    // (P3 of the last tile already drained vmcnt and read only dead garbage)

    // epilogue: C/D frag layout col = lane&15, row = 4*(lane>>4) + r.
    // Global col = colBase + ni*64 + wn*16 + lr.
    if constexpr (ROPE) {
        const int dIdx = wn * 16 + lr;                   // uniform per lane
#pragma unroll
        for (int mi = 0; mi < 8; ++mi)
#pragma unroll
            for (int r = 0; r < 4; ++r) {
                size_t row = rowBase + wm * 128 + mi * 16 + (kq << 2) + r;
                float2 cs = tab[row * 64 + dIdx];        // (cos, sin) — no libm here
#pragma unroll
                for (int hp = 0; hp < 2; ++hp) {
                    float x1 = acc[mi][hp * 2 + 0][r];
                    float x2 = acc[mi][hp * 2 + 1][r];
                    size_t c1 = colBase + hp * 128 + wn * 16 + lr;
                    C[row * (size_t)N + c1]      = f2bf(x1 * cs.x - x2 * cs.y);
                    C[row * (size_t)N + c1 + 64] = f2bf(x2 * cs.x + x1 * cs.y);
                }
            }
    } else {
#pragma unroll
        for (int mi = 0; mi < 8; ++mi)
#pragma unroll
            for (int ni = 0; ni < 4; ++ni)
#pragma unroll
                for (int r = 0; r < 4; ++r) {
                    size_t row = rowBase + wm * 128 + mi * 16 + (kq << 2) + r;
                    size_t col = colBase + ni * 64 + wn * 16 + lr;
                    store_out(&C[row * (size_t)N + col], acc[mi][ni][r]);
                }
    }
}

extern "C" void kernel_launch(void* const* d_in, const int* in_sizes, int n_in,
                              void* d_out, int out_size, void* d_ws, size_t ws_size,
                              hipStream_t stream) {
    const float* hidden    = (const float*)d_in[0];   // [T][E] fp32
    const int*   positions = (const int*)d_in[1];     // [T] int32
    const float* w_qkv     = (const float*)d_in[2];   // [E][6144] fp32
    const float* w_o       = (const float*)d_in[3];   // [QSZ][E] fp32
    float* out = (float*)d_out;                       // [T][E] fp32

    // workspace layout (bf16): H 64MB | WqT 32MB | WoT 32MB | Q 64MB = 192MB.
    // RoPE table (4MB float2) ALIASES the WoT region: table live only during
    // GEMM1; WoT transpose runs AFTER GEMM1.
    u16* Hb  = (u16*)d_ws;
    u16* WqT = Hb  + (size_t)T_DIM * E_DIM;
    u16* WoT = WqT + (size_t)QSZ * E_DIM;
    u16* Qb  = WoT + (size_t)E_DIM * QSZ;
    float2* tab = (float2*)WoT;

    // 1) hidden fp32 -> bf16
    convert_f32_bf16<<<2048, 256, 0, stream>>>(hidden, Hb, (size_t)T_DIM * E_DIM / 4);

    // 2) Wq transpose+convert, RoPE table (into WoT space)
    dim3 tb(32, 8);
    transpose_conv<<<dim3(QSZ / 32, E_DIM / 32), tb, 0, stream>>>(w_qkv, WqT, E_DIM, QSZ, QKV_COLS, 0);
    rope_table<<<(T_DIM * 64) / 256, 256, 0, stream>>>(positions, tab);

    // 3) Q = rope(H @ Wq)  (bf16 out, table-lookup RoPE fused in epilogue)
    gemm256<u16, true><<<dim3((T_DIM / 256) * (QSZ / 256)), 512, 0, stream>>>(
        Hb, WqT, Qb, tab, T_DIM, QSZ, E_DIM);

    // 4) Wo transpose+convert (overwrites table region — table now dead)
    transpose_conv<<<dim3(E_DIM / 32, QSZ / 32), tb, 0, stream>>>(w_o, WoT, QSZ, E_DIM, E_DIM, 0);

    // 5) out = Q @ Wo  (fp32 out)
    gemm256<float, false><<<dim3((T_DIM / 256) * (E_DIM / 256)), 512, 0, stream>>>(
        Qb, WoT, out, nullptr, T_DIM, E_DIM, QSZ);
}

// Round 11
// 530.068 us; speedup vs baseline: 1.1483x; 1.0813x over previous
//
#include <hip/hip_runtime.h>
#include <hip/hip_bf16.h>
#include <stdint.h>

// Problem constants (CausalSelfAttention_22703197127379)
#define T_DIM 8192
#define E_DIM 4096
#define NQH   32
#define HD    128
#define QSZ   (NQH * HD)          // 4096
#define QKV_COLS 6144             // Q_SIZE + 2*KV_SIZE (w_qkv leading dim)

typedef unsigned short u16;
typedef __attribute__((ext_vector_type(8))) short   bf16x8;
typedef __attribute__((ext_vector_type(4))) float   f32x4;
typedef __attribute__((ext_vector_type(4))) unsigned short u16x4;

__device__ __forceinline__ u16 f2bf(float f) {
    uint32_t u = __float_as_uint(f);
    u += 0x7fffu + ((u >> 16) & 1u);   // round-to-nearest-even
    return (u16)(u >> 16);
}
__device__ __forceinline__ float bf2f(u16 u) {
    return __uint_as_float(((uint32_t)u) << 16);
}

// async global->LDS, 16 bytes per lane (dest = wave-uniform base + lane*16)
__device__ __forceinline__ void gload_lds16(u16* lds, const u16* g) {
    __builtin_amdgcn_global_load_lds(
        (const __attribute__((address_space(1))) uint32_t*)g,
        (__attribute__((address_space(3))) uint32_t*)lds,
        16, 0, 0);
}

// ---------------- fp32 [K][ldW] (col slice) -> bf16 transposed [N][K] ----------------
// (standalone: used for Wo after GEMM1; Wq handled by the fused prepass)
__global__ void transpose_conv(const float* __restrict__ W, u16* __restrict__ Wt,
                               int K, int N, int ldW, int colOff) {
    __shared__ float tile[32][33];
    const int tx = threadIdx.x, ty = threadIdx.y;
    const int n0 = blockIdx.x * 32, k0 = blockIdx.y * 32;
#pragma unroll
    for (int j = 0; j < 4; ++j) {
        int k = k0 + ty + j * 8;
        tile[ty + j * 8][tx] = W[(size_t)k * ldW + colOff + n0 + tx];
    }
    __syncthreads();
#pragma unroll
    for (int j = 0; j < 4; ++j) {
        int n = n0 + ty + j * 8;
        Wt[(size_t)n * K + k0 + tx] = f2bf(tile[tx][ty + j * 8]);
    }
}

// =================== fused pre-pass: H convert + Wq transpose + RoPE table ===================
// Three independent memory-bound jobs in ONE dispatch (blockIdx-range sections)
// so their HBM traffic queues concurrently (saves 2 launch gaps + ramp tails).
// libm (powf/sincosf) is safe here — no MFMA accumulator live (rounds 6/7
// lesson: NEVER call libm inside the GEMM epilogue).
#define CONV_BLOCKS 2048
#define TWQ_BLOCKS  ((QSZ / 32) * (E_DIM / 32))   // 16384
#define TAB_BLOCKS  ((T_DIM * 64) / 256)          // 2048

__global__ void prepass(const float* __restrict__ hidden, u16* __restrict__ Hb,
                        const float* __restrict__ w_qkv, u16* __restrict__ WqT,
                        const int* __restrict__ pos, float2* __restrict__ tab) {
    __shared__ float tile[32][33];
    const int b = blockIdx.x;
    const int tid = threadIdx.x;
    if (b < CONV_BLOCKS) {
        // --- section 0: hidden fp32 -> bf16, float4-vectorized grid-stride ---
        const size_t n4 = (size_t)T_DIM * E_DIM / 4;   // 8,388,608
        size_t i = (size_t)b * 256 + tid;
        const size_t stride = (size_t)CONV_BLOCKS * 256;
        for (; i < n4; i += stride) {
            float4 v = ((const float4*)hidden)[i];
            u16x4 o;
            o.x = f2bf(v.x); o.y = f2bf(v.y); o.z = f2bf(v.z); o.w = f2bf(v.w);
            ((u16x4*)Hb)[i] = o;
        }
    } else if (b < CONV_BLOCKS + TWQ_BLOCKS) {
        // --- section 1: WqT[n][k] = w_qkv[k][n], n<4096, ldW=6144 ---
        const int t  = b - CONV_BLOCKS;
        const int tx = tid & 31, ty = tid >> 5;
        const int n0 = (t & 127) * 32;      // QSZ/32 = 128 n-tiles
        const int k0 = (t >> 7) * 32;       // E/32   = 128 k-tiles
#pragma unroll
        for (int j = 0; j < 4; ++j) {
            int k = k0 + ty + j * 8;
            tile[ty + j * 8][tx] = w_qkv[(size_t)k * QKV_COLS + n0 + tx];
        }
        __syncthreads();
#pragma unroll
        for (int j = 0; j < 4; ++j) {
            int n = n0 + ty + j * 8;
            WqT[(size_t)n * E_DIM + k0 + tx] = f2bf(tile[tx][ty + j * 8]);
        }
    } else {
        // --- section 2: tab[t][d] = (cos, sin)(pos[t] * theta^(-d/64)) ---
        const int idx = (b - CONV_BLOCKS - TWQ_BLOCKS) * 256 + tid;
        const int t = idx >> 6, d = idx & 63;
        float inv = powf(10000.0f, -(float)d * (1.0f / 64.0f));
        float fr  = (float)pos[t] * inv;
        float s, c;
        sincosf(fr, &s, &c);
        tab[idx] = make_float2(c, s);
    }
}

// ======================= read-ahead 8-phase bf16 GEMM (r8, 227us/GEMM) =======================
// ROUND-8 GEMM RESTORED VERBATIM — measured 227-228us, MfmaUtil 55%, 0 bank
// conflicts. Schedule experiments r9 (same-phase reads: 289us) and r10
// (balanced reads + in-loop vmcnt(0): 259us) both regressed — counted
// vmcnt(4)/(2) with one-ahead reads is the sticky local optimum. DO NOT touch
// the loop structure, read placement, or vmcnt values.
__device__ __forceinline__ void store_out(u16* p, float v)  { *p = f2bf(v); }
__device__ __forceinline__ void store_out(float* p, float v){ *p = v; }

#define BARS()    do { __builtin_amdgcn_sched_barrier(0); __builtin_amdgcn_s_barrier(); } while (0)
#define BARSPUB() do { __builtin_amdgcn_sched_barrier(0); __builtin_amdgcn_s_barrier(); \
                       __builtin_amdgcn_sched_barrier(0); } while (0)
#define VMC(N) asm volatile("s_waitcnt vmcnt(%0)" :: "n"(N) : "memory")

// stage one half-tile (128 rows x 64 K, one operand): 2 gloads/thread
#define STG_A(buf, h, kOff) do { \
    const u16* s_ = sA + (size_t)(h) * 128 * K + (kOff); \
    u16* d_ = dL + (buf) * 32768 + (h) * 8192; \
    gload_lds16(d_, s_); gload_lds16(d_ + 4096, s_ + (size_t)64 * K); } while (0)
#define STG_B(buf, h, kOff) do { \
    const u16* s_ = sB + (size_t)(h) * 128 * K + (kOff); \
    u16* d_ = dL + 16384 + (buf) * 32768 + (h) * 8192; \
    gload_lds16(d_, s_); gload_lds16(d_ + 4096, s_ + (size_t)64 * K); } while (0)

// read A frags mi in [miBase, miBase+4), both K-slices
#define RD_A(buf, miBase, d0, d1) do { _Pragma("unroll") \
    for (int m = 0; m < 4; ++m) { \
        const u16* p_ = lds + (buf) * 32768 + wm * 8192 + ((miBase) + m) * 1024 + aRow; \
        d0[m] = *(const bf16x8*)(p_ + cOf0); \
        d1[m] = *(const bf16x8*)(p_ + cOf1); } } while (0)
// read B frags ni in [niBase, niBase+2), both K-slices.
// B-row = ni*64 + wn*16 + lr -> half = ni>>1, row_in_half = (ni&1)*64+wn*16+lr
#define RD_B(buf, niBase, d0, d1) do { _Pragma("unroll") \
    for (int n = 0; n < 2; ++n) { \
        const int ni_ = (niBase) + n; \
        const u16* p_ = lds + (buf) * 32768 + 16384 + (ni_ >> 1) * 8192 + \
                        ((ni_ & 1) * 64 + wn * 16) * 64 + aRow; \
        d0[n] = *(const bf16x8*)(p_ + cOf0); \
        d1[n] = *(const bf16x8*)(p_ + cOf1); } } while (0)

#define MM(miBase, niBase, A0, A1, B0, B1) do { \
    __builtin_amdgcn_s_setprio(1); \
    _Pragma("unroll") for (int m = 0; m < 4; ++m) \
    _Pragma("unroll") for (int n = 0; n < 2; ++n) { \
        acc[(miBase) + m][(niBase) + n] = __builtin_amdgcn_mfma_f32_16x16x32_bf16( \
            A0[m], B0[n], acc[(miBase) + m][(niBase) + n], 0, 0, 0); \
        acc[(miBase) + m][(niBase) + n] = __builtin_amdgcn_mfma_f32_16x16x32_bf16( \
            A1[m], B1[n], acc[(miBase) + m][(niBase) + n], 0, 0, 0); } \
    __builtin_amdgcn_s_setprio(0); } while (0)

template <typename OutT, bool ROPE>
__global__ __launch_bounds__(512, 2) void gemm256(const u16* __restrict__ A,
                                                  const u16* __restrict__ Bt,
                                                  OutT* __restrict__ C,
                                                  const float2* __restrict__ tab,
                                                  int M, int N, int K) {
    __shared__ u16 lds[65536];   // 2 bufs x (A 256x64 + B 256x64) bf16 = 128 KiB
    const int tid  = threadIdx.x;
    const int lane = tid & 63;
    const int wid  = tid >> 6;
    const int wm = wid >> 2;           // 0..1 -> 128 rows each
    const int wn = wid & 3;            // 0..3 -> 16-col granules (col=ni*64+wn*16+lr)
    const int lr  = lane & 15;
    const int kq  = lane >> 4;         // 0..3
    const int lr7 = lr & 7;
    const int aRow = lr * 64;                       // row offset within half (elems)
    const int cOf0 = ((kq) ^ lr7) << 3;             // K-slice 0 chunk (swizzled)
    const int cOf1 = ((4 + kq) ^ lr7) << 3;         // K-slice 1 chunk

    // XCD-bijective block swizzle (gridDim.x % 8 == 0)
    const int nwg = gridDim.x;
    const int cpx = nwg >> 3;
    const int bid = blockIdx.x;
    const int swz = (bid & 7) * cpx + (bid >> 3);
    const int numM = M >> 8;
    const size_t rowBase = (size_t)(swz % numM) << 8;
    const size_t colBase = (size_t)(swz / numM) << 8;

    // staging addresses: half-tile = 1024 chunks of 16B; thread owns chunks
    // tid (row r0=tid>>3) and tid+512 (row r0+64); src col pre-swizzled.
    const int r0 = tid >> 3;
    const int cS = (((tid & 7) ^ (r0 & 7)) << 3);
    const u16* sA = A  + (rowBase + r0) * (size_t)K + cS;
    const u16* sB = Bt + (colBase + r0) * (size_t)K + cS;
    u16* dL = &lds[0] + tid * 8;       // linear chunk dest (+4096 elems for chunk tid+512)

    f32x4 acc[8][4];
#pragma unroll
    for (int i = 0; i < 8; ++i)
#pragma unroll
        for (int j = 0; j < 4; ++j)
            acc[i][j] = (f32x4){0.f, 0.f, 0.f, 0.f};

    bf16x8 a0K0[4], a0K1[4], a4K0[4], a4K1[4];
    bf16x8 b01eK0[2], b01eK1[2], b01oK0[2], b01oK1[2], b23K0[2], b23K1[2];

    // prologue: buf0 <- tile0, buf1.B <- tile1; drain buf0 (leave buf1.B in
    // flight), publish, then pre-read P0's operands (a03+b01_e of tile0).
    STG_A(0, 0, 0); STG_A(0, 1, 0); STG_B(0, 0, 0); STG_B(0, 1, 0);
    STG_B(1, 0, 64); STG_B(1, 1, 64);
    VMC(4);
    BARSPUB();
    RD_A(0, 0, a0K0, a0K1);
    RD_B(0, 0, b01eK0, b01eK1);

    const int nIter = K >> 7;          // K/128, K % 128 == 0
    for (int it = 0; it < nIter; ++it) {
        const int k1  = ((it << 1) + 1) << 6;                    // tile 2i+1 (always valid)
        const int kt2 = ((it << 1) + 2) << 6;
        const int kt3 = ((it << 1) + 3) << 6;
        const int k2c = (kt2 <= K - 64) ? kt2 : 0;               // clamp OOB tail stages
        const int k3c = (kt3 <= K - 64) ? kt3 : 0;               // (data never consumed)

        // P0: MFMA Q00 (a03,b01_e buf0) ; read b23(buf0) for P1
        STG_A(1, 0, k1);
        BARS();
        RD_B(0, 2, b23K0, b23K1);
        MM(0, 0, a0K0, a0K1, b01eK0, b01eK1);
        // P1: MFMA Q02 (a03,b23) ; read a47(buf0) for P2
        STG_A(1, 1, k1);
        BARS();
        RD_A(0, 4, a4K0, a4K1);
        MM(0, 2, a0K0, a0K1, b23K0, b23K1);
        // P2: MFMA Q42 (a47,b23) ; no reads
        STG_B(0, 0, k2c);
        BARS();
        MM(4, 2, a4K0, a4K1, b23K0, b23K1);
        // P3: drain buf1, publish ; MFMA Q40 (a47,b01_e) ; read a03+b01_o (buf1) for P4
        STG_B(0, 1, k2c);
        VMC(4);
        BARSPUB();
        RD_A(1, 0, a0K0, a0K1);
        RD_B(1, 0, b01oK0, b01oK1);
        MM(4, 0, a4K0, a4K1, b01eK0, b01eK1);
        // P4: MFMA Q00' (a03,b01_o buf1) ; read b23(buf1) for P5
        STG_A(0, 0, k2c);
        BARS();
        RD_B(1, 2, b23K0, b23K1);
        MM(0, 0, a0K0, a0K1, b01oK0, b01oK1);
        // P5: MFMA Q02' ; read a47(buf1) for P6
        STG_A(0, 1, k2c);
        BARS();
        RD_A(1, 4, a4K0, a4K1);
        MM(0, 2, a0K0, a0K1, b23K0, b23K1);
        // P6: MFMA Q42' ; no reads
        STG_B(1, 0, k3c);
        BARS();
        MM(4, 2, a4K0, a4K1, b23K0, b23K1);
        // P7: drain buf0, publish ; MFMA Q40' ; read a03+b01_e (buf0, next tile) for next P0
        STG_B(1, 1, k3c);
        VMC(4);
        BARSPUB();
        RD_A(0, 0, a0K0, a0K1);
        RD_B(0, 0, b01eK0, b01eK1);
        MM(4, 0, a4K0, a4K1, b01oK0, b01oK1);
    }

    asm volatile("s_waitcnt vmcnt(0)" ::: "memory");   // drain leftover stages

    // epilogue: C/D frag layout col = lane&15, row = 4*(lane>>4) + r.
    // Global col = colBase + ni*64 + wn*16 + lr.
    if constexpr (ROPE) {
        const int dIdx = wn * 16 + lr;                   // uniform per lane
#pragma unroll
        for (int mi = 0; mi < 8; ++mi)
#pragma unroll
            for (int r = 0; r < 4; ++r) {
                size_t row = rowBase + wm * 128 + mi * 16 + (kq << 2) + r;
                float2 cs = tab[row * 64 + dIdx];        // (cos, sin) — no libm here
#pragma unroll
                for (int hp = 0; hp < 2; ++hp) {
                    float x1 = acc[mi][hp * 2 + 0][r];
                    float x2 = acc[mi][hp * 2 + 1][r];
                    size_t c1 = colBase + hp * 128 + wn * 16 + lr;
                    C[row * (size_t)N + c1]      = f2bf(x1 * cs.x - x2 * cs.y);
                    C[row * (size_t)N + c1 + 64] = f2bf(x2 * cs.x + x1 * cs.y);
                }
            }
    } else {
#pragma unroll
        for (int mi = 0; mi < 8; ++mi)
#pragma unroll
            for (int ni = 0; ni < 4; ++ni)
#pragma unroll
                for (int r = 0; r < 4; ++r) {
                    size_t row = rowBase + wm * 128 + mi * 16 + (kq << 2) + r;
                    size_t col = colBase + ni * 64 + wn * 16 + lr;
                    store_out(&C[row * (size_t)N + col], acc[mi][ni][r]);
                }
    }
}

extern "C" void kernel_launch(void* const* d_in, const int* in_sizes, int n_in,
                              void* d_out, int out_size, void* d_ws, size_t ws_size,
                              hipStream_t stream) {
    const float* hidden    = (const float*)d_in[0];   // [T][E] fp32
    const int*   positions = (const int*)d_in[1];     // [T] int32
    const float* w_qkv     = (const float*)d_in[2];   // [E][6144] fp32
    const float* w_o       = (const float*)d_in[3];   // [QSZ][E] fp32
    float* out = (float*)d_out;                       // [T][E] fp32

    // workspace layout (bf16): H 64MB | WqT 32MB | WoT 32MB | Q 64MB = 192MB.
    // RoPE table (4MB float2) ALIASES the WoT region: table live only during
    // GEMM1; WoT transpose runs AFTER GEMM1.
    u16* Hb  = (u16*)d_ws;
    u16* WqT = Hb  + (size_t)T_DIM * E_DIM;
    u16* WoT = WqT + (size_t)QSZ * E_DIM;
    u16* Qb  = WoT + (size_t)E_DIM * QSZ;
    float2* tab = (float2*)WoT;

    // 1) fused pre-pass: H convert + Wq transpose + RoPE table (one dispatch)
    prepass<<<CONV_BLOCKS + TWQ_BLOCKS + TAB_BLOCKS, 256, 0, stream>>>(
        hidden, Hb, w_qkv, WqT, positions, tab);

    // 2) Q = rope(H @ Wq)  (bf16 out, table-lookup RoPE fused in epilogue)
    gemm256<u16, true><<<dim3((T_DIM / 256) * (QSZ / 256)), 512, 0, stream>>>(
        Hb, WqT, Qb, tab, T_DIM, QSZ, E_DIM);

    // 3) Wo transpose+convert (overwrites table region — table now dead)
    dim3 tb(32, 8);
    transpose_conv<<<dim3(E_DIM / 32, QSZ / 32), tb, 0, stream>>>(w_o, WoT, QSZ, E_DIM, E_DIM, 0);

    // 4) out = Q @ Wo  (fp32 out)
    gemm256<float, false><<<dim3((T_DIM / 256) * (E_DIM / 256)), 512, 0, stream>>>(
        Qb, WoT, out, nullptr, T_DIM, E_DIM, QSZ);
}